// Round 3
// baseline (117.945 us; speedup 1.0000x reference)
//
#include <hip/hip_runtime.h>
#include <stdint.h>

// Problem constants (fixed by reference)
#define NB 32    // batch
#define NC 64    // input channels
#define NH 64
#define NW 64
#define NO 512   // output channels
#define HP 66    // h-padded rows (1 zero row top+bottom)

typedef __bf16 bf16x8 __attribute__((ext_vector_type(8)));
typedef short  s16x8  __attribute__((ext_vector_type(8)));
typedef float  f32x4  __attribute__((ext_vector_type(4)));

__device__ __forceinline__ uint16_t f2bf(float f) {
  uint32_t u = __builtin_bit_cast(uint32_t, f);
  u += 0x7fffu + ((u >> 16) & 1u);   // round-to-nearest-even
  return (uint16_t)(u >> 16);
}

// async global->LDS, 16B per lane. LDS dest = wave-uniform base + lane*16.
__device__ __forceinline__ void gld16(const uint16_t* g, uint16_t* l) {
  __builtin_amdgcn_global_load_lds(
      (const __attribute__((address_space(1))) void*)(g),
      (__attribute__((address_space(3))) void*)(l), 16, 0, 0);
}

// ---------------- kernel 1: build effective weights (pre-swizzled) -------
// W_eff[o][c][p] = sum_s coef[o,s]*dict[idx[o,s]][c][p], p = kh*3+kw.
// Global layout matches the LDS tile EXACTLY (staging is a linear DMA):
//   Wl[((p*NO + o)*8 + ((c>>3) ^ (o&7)))*8 + (c&7)]
__global__ void k_build_w(const float* __restrict__ dict,
                          const float* __restrict__ coef,
                          const int*   __restrict__ idx,
                          uint16_t*    __restrict__ Wl) {
  __shared__ float tmp[576];
  const int o = blockIdx.x;
  const int t = threadIdx.x;      // 0..575
  float v = 0.f;
#pragma unroll
  for (int s = 0; s < 4; ++s)
    v += coef[o * 4 + s] * dict[idx[o * 4 + s] * 576 + t];
  tmp[t] = v;
  __syncthreads();
  const int c = t & 63, p = t >> 6;   // 576 = 9*64
  const int sl = ((p * NO + o) * 8 + ((c >> 3) ^ (o & 7))) * 8 + (c & 7);
  Wl[sl] = f2bf(tmp[c * 9 + p]);
}

// ---------------- kernel 2: x NCHW fp32 -> padded swizzled NHWC bf16 -----
// xh[b][hp][w][c] with hp in [0,66), rows 0 and 65 all-zero; within a row,
// 16B chunk (c>>3) stored at chunk position ((c>>3) ^ (w&7)).
__global__ void k_nhwc(const float* __restrict__ x, uint16_t* __restrict__ xh) {
  const int bh = blockIdx.x;            // b*66 + hp
  const int b = bh / HP, hp = bh % HP;
  const int t = threadIdx.x;            // 256
  uint16_t* row = xh + (size_t)(b * HP + hp) * 4096;
  if (hp == 0 || hp == HP - 1) {        // zero pad rows
    int4* r4 = reinterpret_cast<int4*>(row);
    r4[t]       = int4{0, 0, 0, 0};
    r4[t + 256] = int4{0, 0, 0, 0};
    return;
  }
  __shared__ float tile[64][65];
  const int h = hp - 1;
  const int w = t & 63;
#pragma unroll
  for (int c = (t >> 6); c < 64; c += 4)
    tile[c][w] = x[((size_t)(b * NC + c) * NH + h) * NW + w];
  __syncthreads();
#pragma unroll
  for (int i = 0; i < 2; ++i) {
    const int s = t + i * 256;          // 512 slots of 16B
    const int w2 = s >> 3, cb = s & 7;
    uint32_t d[4];
#pragma unroll
    for (int j = 0; j < 4; ++j) {
      const uint32_t lo = f2bf(tile[cb * 8 + 2 * j][w2]);
      const uint32_t hi = f2bf(tile[cb * 8 + 2 * j + 1][w2]);
      d[j] = lo | (hi << 16);
    }
    reinterpret_cast<int4*>(row)[w2 * 8 + (cb ^ (w2 & 7))] =
        int4{(int)d[0], (int)d[1], (int)d[2], (int)d[3]};
  }
}

// ---------------- kernel 3: implicit-GEMM conv ----------------
// Block: 128 o x 512 pixels (8 h-rows of one b), 8 waves (512 thr).
// Per wave: 64 o x 128 pix (2 h-rows), acc[4][8] f32x4.
// xs: x rows h0-1..h0+8, [10][66 w-slots][64 c] bf16, staged once (linear DMA
//     from padded/pre-swizzled xh; w-halo slots zeroed by ds_write).
// as: Wl tap slice [128 o][64 c] bf16, 3 buffers, counted-vmcnt pipeline:
//     per tap: waitcnt vmcnt(2) ; barrier ; issue A(p+2) ; compute tap p.
__global__ __launch_bounds__(512, 2) void k_conv(
    const uint16_t* __restrict__ xh,   // [NB][66][64][64] bf16, pre-swizzled
    const uint16_t* __restrict__ Wl,   // [9][512][64] bf16, pre-swizzled
    const float*    __restrict__ bias,
    float*          __restrict__ out) {
  __shared__ __align__(16) uint16_t xs[10 * 66 * 64];     // 84.4 KB
  __shared__ __align__(16) uint16_t as[3 * 128 * 64];     // 48 KB

  const int t = threadIdx.x;
  // XCD-chunked swizzle: XCD k gets contiguous s-range (its x slice L2-fits)
  const int flat = blockIdx.x;                 // 1024 blocks
  const int s    = (flat & 7) * 128 + (flat >> 3);
  const int ot   = s & 3;                      // o-tile
  const int gy   = s >> 2;                     // pixel tile: b * 8 + h-octet
  const int o0 = ot * 128;
  const int b  = gy >> 3;
  const int h0 = (gy & 7) * 8;

  const int lane = t & 63;
  const int wid  = t >> 6;      // 0..7

  // ---- zero the w-halo slots (slot 0 and 65 of each of 10 rows) ----
  if (t < 160) {
    const int r = t >> 4, sl = (t >> 3) & 1, j = t & 7;
    reinterpret_cast<int4*>(xs)[r * 528 + sl * 520 + j] = int4{0, 0, 0, 0};
  }

  // ---- stage x interior: rows 0..7 -> wave wid; rows 8,9 split ----
  {
    const uint16_t* srow = xh + (size_t)(b * HP + h0 + wid) * 4096;
    uint16_t* drow = xs + wid * 4224 + 64;     // skip w-halo slot 0
#pragma unroll
    for (int k = 0; k < 8; ++k)
      gld16(srow + k * 512 + lane * 8, drow + k * 512);
    const int r2 = 8 + (wid >> 2);
    const int kb = (wid & 3) * 2;
    const uint16_t* srow2 = xh + (size_t)(b * HP + h0 + r2) * 4096;
    uint16_t* drow2 = xs + r2 * 4224 + 64;
    gld16(srow2 + kb * 512 + lane * 8, drow2 + kb * 512);
    gld16(srow2 + (kb + 1) * 512 + lane * 8, drow2 + (kb + 1) * 512);
  }
  asm volatile("" ::: "memory");   // keep x-loads older than A-loads (vmcnt order)

  // ---- A staging: wave wid stages chunks wid*2, wid*2+1 (1KB each) ----
  auto stage_a = [&](int p, int bufsel) {
    const uint16_t* src = Wl + (size_t)p * 32768 + o0 * 64;
    uint16_t* dst = as + bufsel * 8192;
#pragma unroll
    for (int j = 0; j < 2; ++j) {
      const int ch = wid * 2 + j;
      gld16(src + ch * 512 + lane * 8, dst + ch * 512);
    }
  };
  stage_a(0, 0);
  asm volatile("" ::: "memory");
  stage_a(1, 1);
  asm volatile("" ::: "memory");

  const int wm  = wid & 1;      // o sub-block (64 each)
  const int wn  = wid >> 1;     // h-row-pair index 0..3
  const int l15 = lane & 15;
  const int g   = lane >> 4;    // k-group

  f32x4 acc[4][8] = {};

#pragma unroll
  for (int p = 0; p < 9; ++p) {
    // A(p) landed (newest 2 outstanding = A(p+1)); all waves past tap p-1.
    if (p == 0)      asm volatile("s_waitcnt vmcnt(2) lgkmcnt(0)" ::: "memory");
    else if (p == 8) asm volatile("s_waitcnt vmcnt(0)" ::: "memory");
    else             asm volatile("s_waitcnt vmcnt(2)" ::: "memory");
    __builtin_amdgcn_s_barrier();
    asm volatile("" ::: "memory");   // no memory op crosses the barrier

    if (p + 2 <= 8) stage_a(p + 2, (p + 2) % 3);  // overwrites buf read at p-1

    const int dh = p / 3 - 1, dw = p % 3 - 1;
    const uint16_t* asb = as + (p % 3) * 8192;

#pragma unroll
    for (int q = 0; q < 2; ++q) {              // two c-halves of 32
      bf16x8 af[4], bfr[8];
#pragma unroll
      for (int m = 0; m < 4; ++m) {
        const int orow = wm * 64 + m * 16 + l15;
        const int cb = (q * 4 + g) ^ (orow & 7);
        af[m] = __builtin_bit_cast(bf16x8,
            *reinterpret_cast<const s16x8*>(asb + orow * 64 + cb * 8));
      }
#pragma unroll
      for (int n = 0; n < 8; ++n) {
        const int row = wn * 2 + (n >> 2) + dh + 1;   // xs row, in [0,10)
        const int wv  = (n & 3) * 16 + l15 + dw;      // -1..64 -> zero slots
        const int cb  = (q * 4 + g) ^ (wv & 7);
        bfr[n] = __builtin_bit_cast(bf16x8,
            *reinterpret_cast<const s16x8*>(xs + row * 4224 + (wv + 1) * 64 + cb * 8));
      }
      __builtin_amdgcn_s_setprio(1);
#pragma unroll
      for (int m = 0; m < 4; ++m)
#pragma unroll
        for (int n = 0; n < 8; ++n)
          acc[m][n] = __builtin_amdgcn_mfma_f32_16x16x32_bf16(
              af[m], bfr[n], acc[m][n], 0, 0, 0);
      __builtin_amdgcn_s_setprio(0);
    }
  }

  // ---- epilogue: bias + store ----
  // D layout (verified r1/r2): col = lane&15 (pixel), row = g*4 + reg (o)
  const int hb = h0 + wn * 2;
#pragma unroll
  for (int m = 0; m < 4; ++m) {
#pragma unroll
    for (int rr = 0; rr < 4; ++rr) {
      const int o = o0 + wm * 64 + m * 16 + g * 4 + rr;
      const float bv = bias[o];
      float* op = out + ((size_t)(b * NO + o) * NH + hb) * NW;
#pragma unroll
      for (int n = 0; n < 8; ++n)
        op[(n >> 2) * NW + (n & 3) * 16 + l15] = acc[m][n][rr] + bv;
    }
  }
}

extern "C" void kernel_launch(void* const* d_in, const int* in_sizes, int n_in,
                              void* d_out, int out_size, void* d_ws, size_t ws_size,
                              hipStream_t stream) {
  const float* x    = (const float*)d_in[0];
  const float* dict = (const float*)d_in[1];
  const float* coef = (const float*)d_in[2];
  const float* bias = (const float*)d_in[3];
  const int*   idx  = (const int*)d_in[4];
  float* out = (float*)d_out;

  // workspace: xh padded/swizzled = 32*66*4096*2 B = 16.5 MiB at 0;
  //            Wl swizzled 576 KiB at +18 MiB
  uint16_t* xh = (uint16_t*)d_ws;
  uint16_t* Wl = (uint16_t*)((char*)d_ws + (18u << 20));

  hipLaunchKernelGGL(k_build_w, dim3(NO), dim3(576), 0, stream, dict, coef, idx, Wl);
  hipLaunchKernelGGL(k_nhwc, dim3(NB * HP), dim3(256), 0, stream, x, xh);
  hipLaunchKernelGGL(k_conv, dim3(1024), dim3(512), 0, stream, xh, Wl, bias, out);
}

// Round 4
// 112.958 us; speedup vs baseline: 1.0441x; 1.0441x over previous
//
#include <hip/hip_runtime.h>
#include <stdint.h>

// Problem constants (fixed by reference)
#define NB 32    // batch
#define NC 64    // input channels
#define NH 64
#define NW 64
#define NO 512   // output channels
#define HP 66    // h-padded rows (1 zero row top+bottom)

typedef __bf16 bf16x8 __attribute__((ext_vector_type(8)));
typedef short  s16x8  __attribute__((ext_vector_type(8)));
typedef float  f32x4  __attribute__((ext_vector_type(4)));

__device__ __forceinline__ uint16_t f2bf(float f) {
  uint32_t u = __builtin_bit_cast(uint32_t, f);
  u += 0x7fffu + ((u >> 16) & 1u);   // round-to-nearest-even
  return (uint16_t)(u >> 16);
}

// async global->LDS, 16B per lane. LDS dest = wave-uniform base + lane*16.
__device__ __forceinline__ void gld16(const uint16_t* g, uint16_t* l) {
  __builtin_amdgcn_global_load_lds(
      (const __attribute__((address_space(1))) void*)(g),
      (__attribute__((address_space(3))) void*)(l), 16, 0, 0);
}

// ---------------- kernel 1: build effective weights (pre-swizzled) -------
// W_eff[o][c][p] = sum_s coef[o,s]*dict[idx[o,s]][c][p], p = kh*3+kw.
// Global layout matches the LDS tile EXACTLY (staging is a linear DMA):
//   Wl[((p*NO + o)*8 + ((c>>3) ^ (o&7)))*8 + (c&7)]
__global__ void k_build_w(const float* __restrict__ dict,
                          const float* __restrict__ coef,
                          const int*   __restrict__ idx,
                          uint16_t*    __restrict__ Wl) {
  __shared__ float tmp[576];
  const int o = blockIdx.x;
  const int t = threadIdx.x;      // 0..575
  float v = 0.f;
#pragma unroll
  for (int s = 0; s < 4; ++s)
    v += coef[o * 4 + s] * dict[idx[o * 4 + s] * 576 + t];
  tmp[t] = v;
  __syncthreads();
  const int c = t & 63, p = t >> 6;   // 576 = 9*64
  const int sl = ((p * NO + o) * 8 + ((c >> 3) ^ (o & 7))) * 8 + (c & 7);
  Wl[sl] = f2bf(tmp[c * 9 + p]);
}

// ---------------- kernel 2: x NCHW fp32 -> padded swizzled NHWC bf16 -----
// xh[b][hp][w][c] with hp in [0,66), rows 0 and 65 all-zero; within a row,
// 16B chunk (c>>3) stored at chunk position ((c>>3) ^ (w&7)).
__global__ void k_nhwc(const float* __restrict__ x, uint16_t* __restrict__ xh) {
  const int bh = blockIdx.x;            // b*66 + hp
  const int b = bh / HP, hp = bh % HP;
  const int t = threadIdx.x;            // 256
  uint16_t* row = xh + (size_t)(b * HP + hp) * 4096;
  if (hp == 0 || hp == HP - 1) {        // zero pad rows
    int4* r4 = reinterpret_cast<int4*>(row);
    r4[t]       = int4{0, 0, 0, 0};
    r4[t + 256] = int4{0, 0, 0, 0};
    return;
  }
  __shared__ float tile[64][65];
  const int h = hp - 1;
  const int w = t & 63;
#pragma unroll
  for (int c = (t >> 6); c < 64; c += 4)
    tile[c][w] = x[((size_t)(b * NC + c) * NH + h) * NW + w];
  __syncthreads();
#pragma unroll
  for (int i = 0; i < 2; ++i) {
    const int s = t + i * 256;          // 512 slots of 16B
    const int w2 = s >> 3, cb = s & 7;
    uint32_t d[4];
#pragma unroll
    for (int j = 0; j < 4; ++j) {
      const uint32_t lo = f2bf(tile[cb * 8 + 2 * j][w2]);
      const uint32_t hi = f2bf(tile[cb * 8 + 2 * j + 1][w2]);
      d[j] = lo | (hi << 16);
    }
    reinterpret_cast<int4*>(row)[w2 * 8 + (cb ^ (w2 & 7))] =
        int4{(int)d[0], (int)d[1], (int)d[2], (int)d[3]};
  }
}

// ---------------- kernel 3: implicit-GEMM conv, dw-major tap groups ------
// Block: 128 o x 512 pixels (8 h-rows of one b), 8 waves (512 thr).
// Per wave: 64 o x 128 pix (2 h-rows), acc[4][8] f32x4.
// xs: x rows h0-1..h0+8, [10][66 w-slots][64 c] bf16, staged once.
// as: one dw-group = taps (dh=0,1,2) at fixed dw: [3][128][64] bf16 (48 KB),
//     single-buffered; restaged between groups with two __syncthreads().
// Within a group: NO barriers/fences -> braw[4][4] xs-fragments are loaded
// once per q and shared across the 3 dh taps (CSE'd row overlap), and the
// compiler freely interleaves 56 ds_reads with 192 MFMAs per wave.
__global__ __launch_bounds__(512, 2) void k_conv(
    const uint16_t* __restrict__ xh,   // [NB][66][64][64] bf16, pre-swizzled
    const uint16_t* __restrict__ Wl,   // [9][512][64] bf16, pre-swizzled
    const float*    __restrict__ bias,
    float*          __restrict__ out) {
  __shared__ __align__(16) uint16_t xs[10 * 66 * 64];     // 84.4 KB
  __shared__ __align__(16) uint16_t as[3 * 128 * 64];     // 48 KB

  const int t = threadIdx.x;
  // XCD-chunked swizzle: XCD k gets a contiguous s-range (4 b's, L2-resident)
  const int flat = blockIdx.x;                 // 1024 blocks
  const int s    = (flat & 7) * 128 + (flat >> 3);
  const int ot   = s & 3;                      // o-tile
  const int gy   = s >> 2;                     // pixel tile: b * 8 + h-octet
  const int o0 = ot * 128;
  const int b  = gy >> 3;
  const int h0 = (gy & 7) * 8;

  const int lane = t & 63;
  const int wid  = t >> 6;      // 0..7

  // ---- zero the w-halo slots (slot 0 and 65 of each of 10 rows) ----
  if (t < 160) {
    const int r = t >> 4, sl = (t >> 3) & 1, j = t & 7;
    reinterpret_cast<int4*>(xs)[r * 528 + sl * 520 + j] = int4{0, 0, 0, 0};
  }

  // ---- stage x interior: rows 0..7 -> wave wid; rows 8,9 split ----
  {
    const uint16_t* srow = xh + (size_t)(b * HP + h0 + wid) * 4096;
    uint16_t* drow = xs + wid * 4224 + 64;     // skip w-halo slot 0
#pragma unroll
    for (int k = 0; k < 8; ++k)
      gld16(srow + k * 512 + lane * 8, drow + k * 512);
    const int r2 = 8 + (wid >> 2);
    const int kb = (wid & 3) * 2;
    const uint16_t* srow2 = xh + (size_t)(b * HP + h0 + r2) * 4096;
    uint16_t* drow2 = xs + r2 * 4224 + 64;
    gld16(srow2 + kb * 512 + lane * 8, drow2 + kb * 512);
    gld16(srow2 + (kb + 1) * 512 + lane * 8, drow2 + (kb + 1) * 512);
  }

  // ---- A-group staging: group g holds taps p = dh*3 + g, dh = 0..2 ----
  // 48 chunks of 1 KB; wave wid takes chunks wid*6 .. wid*6+5.
  auto stage_a = [&](int g) {
#pragma unroll
    for (int j = 0; j < 6; ++j) {
      const int c = wid * 6 + j;         // 0..47
      const int tap = c >> 4, k = c & 15;
      const uint16_t* src =
          Wl + (size_t)(tap * 3 + g) * 32768 + o0 * 64 + k * 512;
      gld16(src + lane * 8, as + tap * 8192 + k * 512);
    }
  };
  stage_a(0);

  const int wm  = wid & 1;      // o sub-block (64 each)
  const int wn  = wid >> 1;     // h-row-pair index 0..3
  const int l15 = lane & 15;
  const int lg  = lane >> 4;    // k-group

  f32x4 acc[4][8] = {};

  __syncthreads();              // x + A(group0) resident

#pragma unroll
  for (int g = 0; g < 3; ++g) {
    const int dw = g - 1;

#pragma unroll
    for (int q = 0; q < 2; ++q) {              // two c-halves of 32
      // braw[rr][nw]: xs rows wn*2+rr (rr=0..3), shared by all 3 dh taps
      bf16x8 braw[4][4];
#pragma unroll
      for (int rr = 0; rr < 4; ++rr) {
        const int rbase = (wn * 2 + rr) * 4224;
#pragma unroll
        for (int nw = 0; nw < 4; ++nw) {
          const int wv = nw * 16 + l15 + dw;   // -1..64 -> zero halo slots
          const int cb = (q * 4 + lg) ^ (wv & 7);
          braw[rr][nw] = __builtin_bit_cast(bf16x8,
              *reinterpret_cast<const s16x8*>(xs + rbase + (wv + 1) * 64 + cb * 8));
        }
      }
#pragma unroll
      for (int dh = 0; dh < 3; ++dh) {
        bf16x8 af[4];
#pragma unroll
        for (int m = 0; m < 4; ++m) {
          const int orow = wm * 64 + m * 16 + l15;
          const int cb = (q * 4 + lg) ^ (orow & 7);
          af[m] = __builtin_bit_cast(bf16x8,
              *reinterpret_cast<const s16x8*>(as + dh * 8192 + orow * 64 + cb * 8));
        }
#pragma unroll
        for (int m = 0; m < 4; ++m)
#pragma unroll
          for (int n = 0; n < 8; ++n)
            acc[m][n] = __builtin_amdgcn_mfma_f32_16x16x32_bf16(
                af[m], braw[(n >> 2) + dh][n & 3], acc[m][n], 0, 0, 0);
      }
    }

    if (g < 2) {
      __syncthreads();          // all waves done reading as (group g)
      stage_a(g + 1);
      __syncthreads();          // vmcnt(0)+barrier: group g+1 resident
    }
  }

  // ---- epilogue: bias + store ----
  // D layout (verified r1-r3): col = lane&15 (pixel), row = lg*4 + reg (o)
  const int hb = h0 + wn * 2;
#pragma unroll
  for (int m = 0; m < 4; ++m) {
#pragma unroll
    for (int rr = 0; rr < 4; ++rr) {
      const int o = o0 + wm * 64 + m * 16 + lg * 4 + rr;
      const float bv = bias[o];
      float* op = out + ((size_t)(b * NO + o) * NH + hb) * NW;
#pragma unroll
      for (int n = 0; n < 8; ++n)
        op[(n >> 2) * NW + (n & 3) * 16 + l15] = acc[m][n][rr] + bv;
    }
  }
}

extern "C" void kernel_launch(void* const* d_in, const int* in_sizes, int n_in,
                              void* d_out, int out_size, void* d_ws, size_t ws_size,
                              hipStream_t stream) {
  const float* x    = (const float*)d_in[0];
  const float* dict = (const float*)d_in[1];
  const float* coef = (const float*)d_in[2];
  const float* bias = (const float*)d_in[3];
  const int*   idx  = (const int*)d_in[4];
  float* out = (float*)d_out;

  // workspace: xh padded/swizzled = 32*66*4096*2 B = 16.5 MiB at 0;
  //            Wl swizzled 576 KiB at +18 MiB
  uint16_t* xh = (uint16_t*)d_ws;
  uint16_t* Wl = (uint16_t*)((char*)d_ws + (18u << 20));

  hipLaunchKernelGGL(k_build_w, dim3(NO), dim3(576), 0, stream, dict, coef, idx, Wl);
  hipLaunchKernelGGL(k_nhwc, dim3(NB * HP), dim3(256), 0, stream, x, xh);
  hipLaunchKernelGGL(k_conv, dim3(1024), dim3(512), 0, stream, xh, Wl, bias, out);
}